// Round 4
// baseline (2391.143 us; speedup 1.0000x reference)
//
#include <hip/hip_runtime.h>
#include <math.h>

#define N_NODES 661
#define N_GRAPH 128
#define DEG 8
#define EPG (N_NODES*DEG)          // 5288 edges per graph per matrix
#define NTOT (N_NODES*N_GRAPH)     // 84608 nodes
#define FDIM 64
#define NF ((size_t)NTOT*FDIM)     // elements per [n,64] array

using short8  = __attribute__((ext_vector_type(8))) short;
using float4v = __attribute__((ext_vector_type(4))) float;

__device__ __forceinline__ unsigned short f2bf(float x) {
    unsigned int u = __float_as_uint(x);
    unsigned int r = u + 0x7FFFu + ((u >> 16) & 1u);
    return (unsigned short)(r >> 16);
}
__device__ __forceinline__ float bf2f(unsigned short h) {
    return __uint_as_float(((unsigned int)h) << 16);
}

// ---------------------------------------------------------------------------
// Kernel 0: bf16 hi/lo B-fragments of W1/W2 in MFMA B-layout; zero partials.
// ---------------------------------------------------------------------------
__global__ __launch_bounds__(256) void wtrans(
    const float* __restrict__ W1, const float* __restrict__ W2,
    unsigned short* __restrict__ Wb1h, unsigned short* __restrict__ Wb1l,
    unsigned short* __restrict__ Wb2h, unsigned short* __restrict__ Wb2l,
    float* __restrict__ partials)
{
    int i = blockIdx.x*256 + threadIdx.x;     // 0..20479
    if (i < 20480) {
        int j    = i & 7;
        int lane = (i >> 3) & 63;
        int ot   = (i >> 9) & 3;
        int ks   = i >> 11;
        int k = ks*32 + (lane >> 4)*8 + j;
        int o = ot*16 + (lane & 15);
        float w1 = W1[o*320 + k];
        float w2 = W2[o*320 + k];
        unsigned short h1 = f2bf(w1); Wb1h[i] = h1; Wb1l[i] = f2bf(w1 - bf2f(h1));
        unsigned short h2 = f2bf(w2); Wb2h[i] = h2; Wb2l[i] = f2bf(w2 - bf2f(h2));
    }
    if (blockIdx.x == 0) {
        for (int j2 = threadIdx.x; j2 < 1024; j2 += 256) partials[j2] = 0.f;
    }
}

// ---------------------------------------------------------------------------
// Kernel S1: per (graph, 8-feat chunk) LDS scatter of G and B edges into
// u=eG+fB, w=fG+eB, p=eG-fB, then fused node_math epilogue writing
// e3, new_e, f3, new_f + attention partials (4 atomics per block).
// ---------------------------------------------------------------------------
__global__ __launch_bounds__(256) void scatter_gb(
    const float* __restrict__ e, const float* __restrict__ f,
    const float* __restrict__ Gd, const float* __restrict__ Bd,
    const float* __restrict__ Pd, const float* __restrict__ Qd,
    const float* __restrict__ w_ae, const float* __restrict__ w_af,
    const int* __restrict__ rG, const int* __restrict__ cG, const float* __restrict__ vG,
    const int* __restrict__ rB, const int* __restrict__ cB, const float* __restrict__ vB,
    float* __restrict__ arrs, float* __restrict__ partials)
{
    __shared__ float su[N_NODES*8];
    __shared__ float sw[N_NODES*8];
    __shared__ float sp[N_NODES*8];
    __shared__ float sred[8];

    int bid = blockIdx.x;
    int g  = bid >> 3;        // graph
    int fc = bid & 7;         // feature chunk (8 feats)
    int tid = threadIdx.x;
    int slot = tid >> 3;      // 0..31 (edge / node slot)
    int fl   = tid & 7;       // feature lane within chunk
    int feat = fc*8 + fl;
    int ebase = g*EPG;
    int gbase = g*N_NODES;

    for (int i = tid; i < N_NODES*8; i += 256) {
        su[i] = 0.f; sw[i] = 0.f; sp[i] = 0.f;
    }
    __syncthreads();

    // G edges: u += v*e[c], w += v*f[c], p += v*e[c]
    for (int i = slot; i < EPG; i += 32) {
        int r = rG[ebase+i] - gbase;
        int c = cG[ebase+i];
        float v = vG[ebase+i];
        float ex = e[(size_t)c*FDIM + feat];
        float fx = f[(size_t)c*FDIM + feat];
        float a1 = v*ex, a2 = v*fx;
        int a = r*8 + fl;
        atomicAdd(&su[a], a1);
        atomicAdd(&sp[a], a1);
        atomicAdd(&sw[a], a2);
    }
    // B edges: u += v*f[c], w += v*e[c], p -= v*f[c]
    for (int i = slot; i < EPG; i += 32) {
        int r = rB[ebase+i] - gbase;
        int c = cB[ebase+i];
        float v = vB[ebase+i];
        float ex = e[(size_t)c*FDIM + feat];
        float fx = f[(size_t)c*FDIM + feat];
        float a1 = v*fx, a2 = v*ex;
        int a = r*8 + fl;
        atomicAdd(&su[a], a1);
        atomicAdd(&sw[a], a2);
        atomicAdd(&sp[a], -a1);
    }
    __syncthreads();

    // epilogue: node math + write 4 arrays + attention partial accumulation
    float wa = w_ae[feat], wf = w_af[feat];
    float pa0 = 0.f, pa1 = 0.f, pa2 = 0.f, pa3 = 0.f;
    for (int r = slot; r < N_NODES; r += 32) {
        int node = gbase + r;
        size_t idx = (size_t)node*FDIM + feat;
        int a = r*8 + fl;
        float u = su[a], w = sw[a], p = sp[a];
        float ev = e[idx], fv = f[idx];
        float gd = Gd[node], bd = Bd[node], pd = Pd[node], qd = Qd[node];

        float invb = 1.0f/(ev*ev + fv*fv + 0.1f);
        float alpha = (pd*ev + qd*fv)*invb - u;
        float beta  = (qd*ev - pd*fv)*invb + w;
        float invg = 1.0f/(gd*gd + bd*bd);
        float e3v = (alpha*gd + beta*bd)*invg;
        float f3v = (beta*gd - alpha*bd)*invg;
        float vv = ev*ev + fv*fv;
        float P_ = pd - vv*gd, Q_ = qd + vv*bd;
        float nev = (P_*p + Q_*w)*invg;
        float nfv = (P_*w - Q_*p)*invg;

        arrs[0*NF + idx] = e3v;
        arrs[1*NF + idx] = nev;
        arrs[4*NF + idx] = f3v;
        arrs[5*NF + idx] = nfv;
        pa0 += e3v; pa1 += nev; pa2 += f3v; pa3 += nfv;
    }
    pa0 *= wa; pa1 *= wa; pa2 *= wf; pa3 *= wf;

    __syncthreads();
    if (tid < 8) sred[tid] = 0.f;
    __syncthreads();
    int lane = tid & 63;
    float v0 = pa0, v1 = pa1, v2 = pa2, v3 = pa3;
    for (int off = 32; off > 0; off >>= 1) {
        v0 += __shfl_down(v0, off); v1 += __shfl_down(v1, off);
        v2 += __shfl_down(v2, off); v3 += __shfl_down(v3, off);
    }
    if (lane == 0) {
        atomicAdd(&sred[0], v0); atomicAdd(&sred[1], v1);
        atomicAdd(&sred[2], v2); atomicAdd(&sred[3], v3);
    }
    __syncthreads();
    if (tid == 0) {
        atomicAdd(&partials[g*8 + 0], sred[0]);
        atomicAdd(&partials[g*8 + 1], sred[1]);
        atomicAdd(&partials[g*8 + 4], sred[2]);
        atomicAdd(&partials[g*8 + 5], sred[3]);
    }
}

// ---------------------------------------------------------------------------
// Kernel S2: per (matrix in {1,2}, graph, 8-feat chunk) LDS scatter for the
// pass-through SpMMs e_m, f_m. Writes arrs[2+m], arrs[6+m] + 2 atomics/block.
// ---------------------------------------------------------------------------
__global__ __launch_bounds__(256) void scatter_12(
    const float* __restrict__ e, const float* __restrict__ f,
    const float* __restrict__ w_ae, const float* __restrict__ w_af,
    const int* __restrict__ r1, const int* __restrict__ c1, const float* __restrict__ v1,
    const int* __restrict__ r2, const int* __restrict__ c2, const float* __restrict__ v2,
    float* __restrict__ arrs, float* __restrict__ partials)
{
    __shared__ float se[N_NODES*8];
    __shared__ float sf[N_NODES*8];
    __shared__ float sred[2];

    int bid = blockIdx.x;
    int m  = bid >> 10;             // 0 -> matrix1, 1 -> matrix2
    int g  = (bid >> 3) & 127;
    int fc = bid & 7;
    int tid = threadIdx.x;
    int slot = tid >> 3;
    int fl   = tid & 7;
    int feat = fc*8 + fl;
    int ebase = g*EPG;
    int gbase = g*N_NODES;

    const int*   rows = m ? r2 : r1;
    const int*   cols = m ? c2 : c1;
    const float* vals = m ? v2 : v1;

    for (int i = tid; i < N_NODES*8; i += 256) { se[i] = 0.f; sf[i] = 0.f; }
    __syncthreads();

    for (int i = slot; i < EPG; i += 32) {
        int r = rows[ebase+i] - gbase;
        int c = cols[ebase+i];
        float v = vals[ebase+i];
        float ex = e[(size_t)c*FDIM + feat];
        float fx = f[(size_t)c*FDIM + feat];
        int a = r*8 + fl;
        atomicAdd(&se[a], v*ex);
        atomicAdd(&sf[a], v*fx);
    }
    __syncthreads();

    float wa = w_ae[feat], wf = w_af[feat];
    float pa0 = 0.f, pa1 = 0.f;
    for (int r = slot; r < N_NODES; r += 32) {
        size_t idx = (size_t)(gbase + r)*FDIM + feat;
        int a = r*8 + fl;
        float ev = se[a], fv = sf[a];
        arrs[(size_t)(2+m)*NF + idx] = ev;
        arrs[(size_t)(6+m)*NF + idx] = fv;
        pa0 += ev; pa1 += fv;
    }
    pa0 *= wa; pa1 *= wf;

    __syncthreads();
    if (tid < 2) sred[tid] = 0.f;
    __syncthreads();
    int lane = tid & 63;
    for (int off = 32; off > 0; off >>= 1) {
        pa0 += __shfl_down(pa0, off); pa1 += __shfl_down(pa1, off);
    }
    if (lane == 0) { atomicAdd(&sred[0], pa0); atomicAdd(&sred[1], pa1); }
    __syncthreads();
    if (tid == 0) {
        atomicAdd(&partials[g*8 + 2 + m], sred[0]);
        atomicAdd(&partials[g*8 + 6 + m], sred[1]);
    }
}

// ---------------------------------------------------------------------------
// Kernel 3: finalize attention weights
// ---------------------------------------------------------------------------
__global__ void attn_final(const float* __restrict__ partials,
                           const float* __restrict__ b_ae, const float* __restrict__ b_af,
                           float* __restrict__ att)
{
    int g = threadIdx.x;
    if (g >= N_GRAPH) return;
    float ae[4], af[4], se = 1e-4f, sf = 1e-4f;
    float bae = b_ae[0], baf = b_af[0];
    #pragma unroll
    for (int j = 0; j < 4; ++j) {
        float x = partials[g*8 + j]*(1.0f/N_NODES) + bae;
        ae[j] = 1.0f/(1.0f + expf(-x)); se += ae[j];
        float y = partials[g*8 + 4 + j]*(1.0f/N_NODES) + baf;
        af[j] = 1.0f/(1.0f + expf(-y)); sf += af[j];
    }
    #pragma unroll
    for (int j = 0; j < 4; ++j) {
        att[g*8 + j]     = ae[j]/se;
        att[g*8 + 4 + j] = af[j]/sf;
    }
}

// ---------------------------------------------------------------------------
// Kernel 4: cat build in LDS + MFMA GEMM (split-bf16 hi/lo) + tanh.
// ---------------------------------------------------------------------------
#define STR 324
__global__ __launch_bounds__(256) void final_fused(
    const float* __restrict__ e, const float* __restrict__ f,
    const float* __restrict__ arrs, const float* __restrict__ att,
    const unsigned short* __restrict__ Wb1h, const unsigned short* __restrict__ Wb1l,
    const unsigned short* __restrict__ Wb2h, const unsigned short* __restrict__ Wb2l,
    const float* __restrict__ bv1, const float* __restrict__ bv2,
    float* __restrict__ out)
{
    __shared__ __align__(16) float cat_e[16*STR];
    __shared__ __align__(16) float cat_f[16*STR];

    int tid = threadIdx.x, lane = tid & 63, chunk = tid >> 6;
    int node0 = blockIdx.x * 16;

    #pragma unroll
    for (int round = 0; round < 4; ++round) {
        int ni = round*4 + chunk;
        int node = node0 + ni;
        int g = node / N_NODES;
        size_t idx = (size_t)node*FDIM + lane;
        float* ce = &cat_e[ni*STR];
        float* cf = &cat_f[ni*STR];
        ce[lane]     = arrs[0*NF + idx]*att[g*8+0];
        ce[64+lane]  = arrs[1*NF + idx]*att[g*8+1];
        ce[128+lane] = arrs[2*NF + idx]*att[g*8+2];
        ce[192+lane] = arrs[3*NF + idx]*att[g*8+3];
        ce[256+lane] = e[idx];
        cf[lane]     = arrs[4*NF + idx]*att[g*8+4];
        cf[64+lane]  = arrs[5*NF + idx]*att[g*8+5];
        cf[128+lane] = arrs[6*NF + idx]*att[g*8+6];
        cf[192+lane] = arrs[7*NF + idx]*att[g*8+7];
        cf[256+lane] = f[idx];
    }
    __syncthreads();

    float4v acc_e = {0.f, 0.f, 0.f, 0.f};
    float4v acc_f = {0.f, 0.f, 0.f, 0.f};
    int m16 = lane & 15, quad = lane >> 4;

    for (int ks = 0; ks < 10; ++ks) {
        const float* ar = &cat_e[m16*STR + ks*32 + quad*8];
        float4 a0 = *(const float4*)ar;
        float4 a1 = *(const float4*)(ar + 4);
        const float* br = &cat_f[m16*STR + ks*32 + quad*8];
        float4 c0 = *(const float4*)br;
        float4 c1 = *(const float4*)(br + 4);

        float av[8] = {a0.x,a0.y,a0.z,a0.w,a1.x,a1.y,a1.z,a1.w};
        float cv[8] = {c0.x,c0.y,c0.z,c0.w,c1.x,c1.y,c1.z,c1.w};
        short8 ah, al, ch, cl;
        #pragma unroll
        for (int j = 0; j < 8; ++j) {
            unsigned short h = f2bf(av[j]);
            ah[j] = (short)h; al[j] = (short)f2bf(av[j] - bf2f(h));
            unsigned short h2 = f2bf(cv[j]);
            ch[j] = (short)h2; cl[j] = (short)f2bf(cv[j] - bf2f(h2));
        }

        size_t boff = (size_t)((ks*4 + chunk)*64 + lane)*8;
        short8 b1h = *(const short8*)(Wb1h + boff);
        short8 b1l = *(const short8*)(Wb1l + boff);
        short8 b2h = *(const short8*)(Wb2h + boff);
        short8 b2l = *(const short8*)(Wb2l + boff);

        acc_e = __builtin_amdgcn_mfma_f32_16x16x32_bf16(ah, b1h, acc_e, 0, 0, 0);
        acc_e = __builtin_amdgcn_mfma_f32_16x16x32_bf16(al, b1h, acc_e, 0, 0, 0);
        acc_e = __builtin_amdgcn_mfma_f32_16x16x32_bf16(ah, b1l, acc_e, 0, 0, 0);
        acc_f = __builtin_amdgcn_mfma_f32_16x16x32_bf16(ch, b2h, acc_f, 0, 0, 0);
        acc_f = __builtin_amdgcn_mfma_f32_16x16x32_bf16(cl, b2h, acc_f, 0, 0, 0);
        acc_f = __builtin_amdgcn_mfma_f32_16x16x32_bf16(ch, b2l, acc_f, 0, 0, 0);
    }

    int o = chunk*16 + m16;
    float be = bv1[o], bf = bv2[o];
    #pragma unroll
    for (int reg = 0; reg < 4; ++reg) {
        int node = node0 + quad*4 + reg;
        out[(size_t)node*FDIM + o]      = tanhf(acc_e[reg] + be);
        out[NF + (size_t)node*FDIM + o] = tanhf(acc_f[reg] + bf);
    }
}

// ---------------------------------------------------------------------------
extern "C" void kernel_launch(void* const* d_in, const int* in_sizes, int n_in,
                              void* d_out, int out_size, void* d_ws, size_t ws_size,
                              hipStream_t stream) {
    (void)in_sizes; (void)n_in; (void)out_size; (void)ws_size;
    const float* e     = (const float*)d_in[0];
    const float* f     = (const float*)d_in[1];
    const int*   rowsG = (const int*)d_in[2];
    const int*   colsG = (const int*)d_in[3];
    const float* valsG = (const float*)d_in[4];
    const int*   rowsB = (const int*)d_in[5];
    const int*   colsB = (const int*)d_in[6];
    const float* valsB = (const float*)d_in[7];
    const int*   rows1 = (const int*)d_in[8];
    const int*   cols1 = (const int*)d_in[9];
    const float* vals1 = (const float*)d_in[10];
    const int*   rows2 = (const int*)d_in[11];
    const int*   cols2 = (const int*)d_in[12];
    const float* vals2 = (const float*)d_in[13];
    const float* G_d   = (const float*)d_in[14];
    const float* B_d   = (const float*)d_in[15];
    const float* Pd    = (const float*)d_in[16];
    const float* Qd    = (const float*)d_in[17];
    const float* W1    = (const float*)d_in[18];
    const float* b1    = (const float*)d_in[19];
    const float* W2    = (const float*)d_in[20];
    const float* b2    = (const float*)d_in[21];
    const float* w_ae  = (const float*)d_in[22];
    const float* b_ae  = (const float*)d_in[23];
    const float* w_af  = (const float*)d_in[24];
    const float* b_af  = (const float*)d_in[25];

    float* ws       = (float*)d_ws;
    float* arrs     = ws;                          // 8*NF
    float* partials = ws + 8*NF;                   // 1024
    float* att      = partials + 1024;             // 1024
    unsigned short* Wb1h = (unsigned short*)(att + 1024);  // 20480 each
    unsigned short* Wb1l = Wb1h + 20480;
    unsigned short* Wb2h = Wb1l + 20480;
    unsigned short* Wb2l = Wb2h + 20480;

    wtrans<<<dim3(80), dim3(256), 0, stream>>>(W1, W2, Wb1h, Wb1l, Wb2h, Wb2l, partials);

    scatter_gb<<<dim3(N_GRAPH*8), dim3(256), 0, stream>>>(
        e, f, G_d, B_d, Pd, Qd, w_ae, w_af,
        rowsG, colsG, valsG, rowsB, colsB, valsB, arrs, partials);

    scatter_12<<<dim3(N_GRAPH*8*2), dim3(256), 0, stream>>>(
        e, f, w_ae, w_af, rows1, cols1, vals1, rows2, cols2, vals2, arrs, partials);

    attn_final<<<dim3(1), dim3(128), 0, stream>>>(partials, b_ae, b_af, att);

    final_fused<<<dim3(NTOT/16), dim3(256), 0, stream>>>(
        e, f, arrs, att, Wb1h, Wb1l, Wb2h, Wb2l, b1, b2, (float*)d_out);
}

// Round 5
// 486.593 us; speedup vs baseline: 4.9141x; 4.9141x over previous
//
#include <hip/hip_runtime.h>
#include <math.h>

#define N_NODES 661
#define N_GRAPH 128
#define DEG 8
#define EPG (N_NODES*DEG)          // 5288 edges per graph per matrix
#define NTOT (N_NODES*N_GRAPH)     // 84608 nodes
#define FDIM 64
#define NF ((size_t)NTOT*FDIM)     // elements per [n,64] array
#define OSTR 672                   // padded CSR offsets stride
#define NTILE 11
#define TROWS 61                   // 11*61 = 671 >= 661

using short8  = __attribute__((ext_vector_type(8))) short;
using float4v = __attribute__((ext_vector_type(4))) float;

__device__ __forceinline__ unsigned short f2bf(float x) {
    unsigned int u = __float_as_uint(x);
    unsigned int r = u + 0x7FFFu + ((u >> 16) & 1u);
    return (unsigned short)(r >> 16);
}
__device__ __forceinline__ float bf2f(unsigned short h) {
    return __uint_as_float(((unsigned int)h) << 16);
}

// ---------------------------------------------------------------------------
// Kernel 0: bf16 hi/lo B-fragments of W1/W2 in MFMA B-layout.
// ---------------------------------------------------------------------------
__global__ __launch_bounds__(256) void wtrans(
    const float* __restrict__ W1, const float* __restrict__ W2,
    unsigned short* __restrict__ Wb1h, unsigned short* __restrict__ Wb1l,
    unsigned short* __restrict__ Wb2h, unsigned short* __restrict__ Wb2l)
{
    int i = blockIdx.x*256 + threadIdx.x;     // 0..20479
    if (i < 20480) {
        int j    = i & 7;
        int lane = (i >> 3) & 63;
        int ot   = (i >> 9) & 3;
        int ks   = i >> 11;
        int k = ks*32 + (lane >> 4)*8 + j;
        int o = ot*16 + (lane & 15);
        float w1 = W1[o*320 + k];
        float w2 = W2[o*320 + k];
        unsigned short h1 = f2bf(w1); Wb1h[i] = h1; Wb1l[i] = f2bf(w1 - bf2f(h1));
        unsigned short h2 = f2bf(w2); Wb2h[i] = h2; Wb2l[i] = f2bf(w2 - bf2f(h2));
    }
}

// ---------------------------------------------------------------------------
// Kernel 1: per-(graph,matrix) LDS counting sort -> CSR in ws (parallel scan).
// ---------------------------------------------------------------------------
__global__ __launch_bounds__(256) void csr_build(
    const int* __restrict__ rG, const int* __restrict__ cG, const float* __restrict__ vG,
    const int* __restrict__ rB, const int* __restrict__ cB, const float* __restrict__ vB,
    const int* __restrict__ r1, const int* __restrict__ c1, const float* __restrict__ v1,
    const int* __restrict__ r2, const int* __restrict__ c2, const float* __restrict__ v2,
    int* __restrict__ offs_out, int2* __restrict__ pairs_out)
{
    __shared__ int   scount[N_NODES];
    __shared__ int   soffs[N_NODES+1];
    __shared__ int   scursor[N_NODES];
    __shared__ int   scol[EPG];
    __shared__ float sval[EPG];
    __shared__ int   sscan[256];

    int bid = blockIdx.x;
    int g = bid & 127;
    int m = bid >> 7;
    const int*   rows = (m==0)?rG:(m==1)?rB:(m==2)?r1:r2;
    const int*   cols = (m==0)?cG:(m==1)?cB:(m==2)?c1:c2;
    const float* vals = (m==0)?vG:(m==1)?vB:(m==2)?v1:v2;

    int tid = threadIdx.x;
    int ebase = g*EPG;
    int gbase = g*N_NODES;
    int seg = m*N_GRAPH + g;

    for (int i = tid; i < N_NODES; i += 256) scount[i] = 0;
    __syncthreads();
    for (int i = tid; i < EPG; i += 256)
        atomicAdd(&scount[rows[ebase+i] - gbase], 1);
    __syncthreads();

    // parallel scan: each thread owns 3 counts; Hillis-Steele over 256 partials
    int c0 = tid*3;
    int ps = 0;
    #pragma unroll
    for (int j = 0; j < 3; ++j) { int i = c0+j; if (i < N_NODES) ps += scount[i]; }
    sscan[tid] = ps;
    __syncthreads();
    #pragma unroll
    for (int d = 1; d < 256; d <<= 1) {
        int v = (tid >= d) ? sscan[tid-d] : 0;
        __syncthreads();
        sscan[tid] += v;
        __syncthreads();
    }
    int run = sscan[tid] - ps;   // exclusive prefix
    #pragma unroll
    for (int j = 0; j < 3; ++j) {
        int i = c0+j;
        if (i < N_NODES) { soffs[i] = run; scursor[i] = run; run += scount[i]; }
    }
    if (tid == 0) soffs[N_NODES] = EPG;
    __syncthreads();

    for (int i = tid; i < EPG; i += 256) {
        int r = rows[ebase+i] - gbase;
        int pos = atomicAdd(&scursor[r], 1);
        scol[pos] = cols[ebase+i];
        sval[pos] = vals[ebase+i];
    }
    __syncthreads();

    for (int i = tid; i <= N_NODES; i += 256)
        offs_out[(size_t)seg*OSTR + i] = soffs[i];
    int2* po = pairs_out + (size_t)seg*EPG;
    for (int i = tid; i < EPG; i += 256)
        po[i] = make_int2(scol[i], __float_as_int(sval[i]));
}

// ---------------------------------------------------------------------------
__device__ __forceinline__ void node_math(
    float ev, float fv, float gd, float bd, float pd, float qd,
    float eGv, float fGv, float eBv, float fBv,
    float& e3v, float& nev, float& f3v, float& nfv)
{
    float invb = 1.0f/(ev*ev + fv*fv + 0.1f);
    float alpha = (pd*ev + qd*fv)*invb - eGv - fBv;
    float beta  = (qd*ev - pd*fv)*invb + fGv + eBv;
    float invg = 1.0f/(gd*gd + bd*bd);
    e3v = (alpha*gd + beta*bd)*invg;
    f3v = (beta*gd - alpha*bd)*invg;
    float bb1 = eGv - fBv, bb2 = fGv + eBv;
    float vv = ev*ev + fv*fv;
    float P_ = pd - vv*gd, Q_ = qd + vv*bd;
    nev = (P_*bb1 + Q_*bb2)*invg;
    nfv = (P_*bb2 - Q_*bb1)*invg;
}

__device__ __forceinline__ void row_gather(
    const int2* __restrict__ pp, int s, int t,
    const float* __restrict__ e, const float* __restrict__ f,
    int lane, float& ae, float& af)
{
    ae = 0.f; af = 0.f;
    for (int base = s; base < t; base += 8) {
        int2  pb[8];
        float ev[8], fv[8];
        #pragma unroll
        for (int j = 0; j < 8; ++j) {
            int kk = base + j;
            pb[j] = pp[(kk < t) ? kk : s];
        }
        #pragma unroll
        for (int j = 0; j < 8; ++j) {
            size_t ci = (size_t)pb[j].x*FDIM + lane;
            ev[j] = e[ci];
            fv[j] = f[ci];
        }
        #pragma unroll
        for (int j = 0; j < 8; ++j) {
            float v = (base + j < t) ? __int_as_float(pb[j].y) : 0.f;
            ae = fmaf(v, ev[j], ae);
            af = fmaf(v, fv[j], af);
        }
    }
}

// ---------------------------------------------------------------------------
// Kernel 2: gather SpMM, 2816 blocks = 8 XCD * (16 graphs * 22 (tile,set)).
// set0: G+B + node_math -> arrs[0,1,4,5]; set1: m1+m2 -> arrs[2,3,6,7].
// Attention partials via block reduce -> unique slots (no atomics).
// ---------------------------------------------------------------------------
__global__ __launch_bounds__(256) void gather_all(
    const float* __restrict__ e, const float* __restrict__ f,
    const float* __restrict__ Gd, const float* __restrict__ Bd,
    const float* __restrict__ Pd, const float* __restrict__ Qd,
    const float* __restrict__ w_ae, const float* __restrict__ w_af,
    const int* __restrict__ offs, const int2* __restrict__ pairs,
    float* __restrict__ arrs, float* __restrict__ partials)
{
    int tid = threadIdx.x, lane = tid & 63, wv = tid >> 6;
    int bid = blockIdx.x;
    int xcd = bid & 7, loc = bid >> 3;          // loc 0..351
    int g    = xcd*16 + (loc/22);
    int sub  = loc % 22;
    int set  = (sub < NTILE) ? 0 : 1;
    int tile = sub - set*NTILE;
    int r0   = tile*TROWS;
    int rlim = min(TROWS, N_NODES - r0);
    int mA = set ? 2 : 0, mB = set ? 3 : 1;

    const int*  poA = offs + (size_t)(mA*N_GRAPH + g)*OSTR;
    const int*  poB = offs + (size_t)(mB*N_GRAPH + g)*OSTR;
    const int2* ppA = pairs + (size_t)(mA*N_GRAPH + g)*EPG;
    const int2* ppB = pairs + (size_t)(mB*N_GRAPH + g)*EPG;

    float pa0 = 0.f, pa1 = 0.f, pa2 = 0.f, pa3 = 0.f;

    for (int lr = wv; lr < rlim; lr += 4) {
        int r = r0 + lr;
        int node = g*N_NODES + r;
        size_t idx = (size_t)node*FDIM + lane;
        int sA = poA[r], tA = poA[r+1];
        int sB = poB[r], tB = poB[r+1];
        float aAe, aAf, aBe, aBf;
        row_gather(ppA, sA, tA, e, f, lane, aAe, aAf);
        row_gather(ppB, sB, tB, e, f, lane, aBe, aBf);

        if (set == 0) {
            float ev = e[idx], fv = f[idx];
            float gd = Gd[node], bd = Bd[node], pd = Pd[node], qd = Qd[node];
            float e3v, nev, f3v, nfv;
            node_math(ev, fv, gd, bd, pd, qd, aAe, aAf, aBe, aBf,
                      e3v, nev, f3v, nfv);
            arrs[0*NF + idx] = e3v;
            arrs[1*NF + idx] = nev;
            arrs[4*NF + idx] = f3v;
            arrs[5*NF + idx] = nfv;
            pa0 += e3v; pa1 += nev; pa2 += f3v; pa3 += nfv;
        } else {
            arrs[2*NF + idx] = aAe;   // e1
            arrs[6*NF + idx] = aAf;   // f1
            arrs[3*NF + idx] = aBe;   // e2
            arrs[7*NF + idx] = aBf;   // f2
            pa0 += aAe; pa1 += aBe; pa2 += aAf; pa3 += aBf;
        }
    }

    float wa = w_ae[lane], wf = w_af[lane];
    pa0 *= wa; pa1 *= wa; pa2 *= wf; pa3 *= wf;

    __shared__ float sred[4];
    if (tid < 4) sred[tid] = 0.f;
    __syncthreads();
    for (int off = 32; off > 0; off >>= 1) {
        pa0 += __shfl_down(pa0, off); pa1 += __shfl_down(pa1, off);
        pa2 += __shfl_down(pa2, off); pa3 += __shfl_down(pa3, off);
    }
    if (lane == 0) {
        atomicAdd(&sred[0], pa0); atomicAdd(&sred[1], pa1);
        atomicAdd(&sred[2], pa2); atomicAdd(&sred[3], pa3);
    }
    __syncthreads();
    if (tid == 0) {
        float* pt = partials + ((size_t)g*NTILE + tile)*8;
        if (set == 0) { pt[0] = sred[0]; pt[1] = sred[1]; pt[4] = sred[2]; pt[5] = sred[3]; }
        else          { pt[2] = sred[0]; pt[3] = sred[1]; pt[6] = sred[2]; pt[7] = sred[3]; }
    }
}

// ---------------------------------------------------------------------------
// Kernel 3: finalize attention weights (sum 11 tile-partials, sigmoid, norm)
// ---------------------------------------------------------------------------
__global__ void attn_final(const float* __restrict__ partials,
                           const float* __restrict__ b_ae, const float* __restrict__ b_af,
                           float* __restrict__ att)
{
    int g = threadIdx.x;
    if (g >= N_GRAPH) return;
    float s[8];
    #pragma unroll
    for (int j = 0; j < 8; ++j) {
        float t = 0.f;
        for (int q = 0; q < NTILE; ++q) t += partials[((size_t)g*NTILE + q)*8 + j];
        s[j] = t;
    }
    float ae[4], af[4], se = 1e-4f, sf = 1e-4f;
    float bae = b_ae[0], baf = b_af[0];
    #pragma unroll
    for (int j = 0; j < 4; ++j) {
        float x = s[j]*(1.0f/N_NODES) + bae;
        ae[j] = 1.0f/(1.0f + expf(-x)); se += ae[j];
        float y = s[4+j]*(1.0f/N_NODES) + baf;
        af[j] = 1.0f/(1.0f + expf(-y)); sf += af[j];
    }
    #pragma unroll
    for (int j = 0; j < 4; ++j) {
        att[g*8 + j]     = ae[j]/se;
        att[g*8 + 4 + j] = af[j]/sf;
    }
}

// ---------------------------------------------------------------------------
// Kernel 4: cat build in LDS + MFMA GEMM (split-bf16 hi/lo) + tanh.
// ---------------------------------------------------------------------------
#define STR 324
__global__ __launch_bounds__(256) void final_fused(
    const float* __restrict__ e, const float* __restrict__ f,
    const float* __restrict__ arrs, const float* __restrict__ att,
    const unsigned short* __restrict__ Wb1h, const unsigned short* __restrict__ Wb1l,
    const unsigned short* __restrict__ Wb2h, const unsigned short* __restrict__ Wb2l,
    const float* __restrict__ bv1, const float* __restrict__ bv2,
    float* __restrict__ out)
{
    __shared__ __align__(16) float cat_e[16*STR];
    __shared__ __align__(16) float cat_f[16*STR];

    int tid = threadIdx.x, lane = tid & 63, chunk = tid >> 6;
    int node0 = blockIdx.x * 16;

    #pragma unroll
    for (int round = 0; round < 4; ++round) {
        int ni = round*4 + chunk;
        int node = node0 + ni;
        int g = node / N_NODES;
        size_t idx = (size_t)node*FDIM + lane;
        float* ce = &cat_e[ni*STR];
        float* cf = &cat_f[ni*STR];
        ce[lane]     = arrs[0*NF + idx]*att[g*8+0];
        ce[64+lane]  = arrs[1*NF + idx]*att[g*8+1];
        ce[128+lane] = arrs[2*NF + idx]*att[g*8+2];
        ce[192+lane] = arrs[3*NF + idx]*att[g*8+3];
        ce[256+lane] = e[idx];
        cf[lane]     = arrs[4*NF + idx]*att[g*8+4];
        cf[64+lane]  = arrs[5*NF + idx]*att[g*8+5];
        cf[128+lane] = arrs[6*NF + idx]*att[g*8+6];
        cf[192+lane] = arrs[7*NF + idx]*att[g*8+7];
        cf[256+lane] = f[idx];
    }
    __syncthreads();

    float4v acc_e = {0.f, 0.f, 0.f, 0.f};
    float4v acc_f = {0.f, 0.f, 0.f, 0.f};
    int m16 = lane & 15, quad = lane >> 4;

    for (int ks = 0; ks < 10; ++ks) {
        const float* ar = &cat_e[m16*STR + ks*32 + quad*8];
        float4 a0 = *(const float4*)ar;
        float4 a1 = *(const float4*)(ar + 4);
        const float* br = &cat_f[m16*STR + ks*32 + quad*8];
        float4 c0 = *(const float4*)br;
        float4 c1 = *(const float4*)(br + 4);

        float av[8] = {a0.x,a0.y,a0.z,a0.w,a1.x,a1.y,a1.z,a1.w};
        float cv[8] = {c0.x,c0.y,c0.z,c0.w,c1.x,c1.y,c1.z,c1.w};
        short8 ah, al, ch, cl;
        #pragma unroll
        for (int j = 0; j < 8; ++j) {
            unsigned short h = f2bf(av[j]);
            ah[j] = (short)h; al[j] = (short)f2bf(av[j] - bf2f(h));
            unsigned short h2 = f2bf(cv[j]);
            ch[j] = (short)h2; cl[j] = (short)f2bf(cv[j] - bf2f(h2));
        }

        size_t boff = (size_t)((ks*4 + chunk)*64 + lane)*8;
        short8 b1h = *(const short8*)(Wb1h + boff);
        short8 b1l = *(const short8*)(Wb1l + boff);
        short8 b2h = *(const short8*)(Wb2h + boff);
        short8 b2l = *(const short8*)(Wb2l + boff);

        acc_e = __builtin_amdgcn_mfma_f32_16x16x32_bf16(ah, b1h, acc_e, 0, 0, 0);
        acc_e = __builtin_amdgcn_mfma_f32_16x16x32_bf16(al, b1h, acc_e, 0, 0, 0);
        acc_e = __builtin_amdgcn_mfma_f32_16x16x32_bf16(ah, b1l, acc_e, 0, 0, 0);
        acc_f = __builtin_amdgcn_mfma_f32_16x16x32_bf16(ch, b2h, acc_f, 0, 0, 0);
        acc_f = __builtin_amdgcn_mfma_f32_16x16x32_bf16(cl, b2h, acc_f, 0, 0, 0);
        acc_f = __builtin_amdgcn_mfma_f32_16x16x32_bf16(ch, b2l, acc_f, 0, 0, 0);
    }

    int o = chunk*16 + m16;
    float be = bv1[o], bf = bv2[o];
    #pragma unroll
    for (int reg = 0; reg < 4; ++reg) {
        int node = node0 + quad*4 + reg;
        out[(size_t)node*FDIM + o]      = tanhf(acc_e[reg] + be);
        out[NF + (size_t)node*FDIM + o] = tanhf(acc_f[reg] + bf);
    }
}

// ---------------------------------------------------------------------------
extern "C" void kernel_launch(void* const* d_in, const int* in_sizes, int n_in,
                              void* d_out, int out_size, void* d_ws, size_t ws_size,
                              hipStream_t stream) {
    (void)in_sizes; (void)n_in; (void)out_size; (void)ws_size;
    const float* e     = (const float*)d_in[0];
    const float* f     = (const float*)d_in[1];
    const int*   rowsG = (const int*)d_in[2];
    const int*   colsG = (const int*)d_in[3];
    const float* valsG = (const float*)d_in[4];
    const int*   rowsB = (const int*)d_in[5];
    const int*   colsB = (const int*)d_in[6];
    const float* valsB = (const float*)d_in[7];
    const int*   rows1 = (const int*)d_in[8];
    const int*   cols1 = (const int*)d_in[9];
    const float* vals1 = (const float*)d_in[10];
    const int*   rows2 = (const int*)d_in[11];
    const int*   cols2 = (const int*)d_in[12];
    const float* vals2 = (const float*)d_in[13];
    const float* G_d   = (const float*)d_in[14];
    const float* B_d   = (const float*)d_in[15];
    const float* Pd    = (const float*)d_in[16];
    const float* Qd    = (const float*)d_in[17];
    const float* W1    = (const float*)d_in[18];
    const float* b1    = (const float*)d_in[19];
    const float* W2    = (const float*)d_in[20];
    const float* b2    = (const float*)d_in[21];
    const float* w_ae  = (const float*)d_in[22];
    const float* b_ae  = (const float*)d_in[23];
    const float* w_af  = (const float*)d_in[24];
    const float* b_af  = (const float*)d_in[25];

    float* ws       = (float*)d_ws;
    float* arrs     = ws;                            // 8*NF
    float* partials = ws + 8*NF;                     // 128*11*8 = 11264
    float* att      = partials + 11264;              // 1024
    unsigned short* Wb1h = (unsigned short*)(att + 1024);  // 20480 shorts each
    unsigned short* Wb1l = Wb1h + 20480;
    unsigned short* Wb2h = Wb1l + 20480;
    unsigned short* Wb2l = Wb2h + 20480;
    int*   offs     = (int*)(Wb2l + 20480);          // 512*OSTR ints
    int2*  pairs    = (int2*)(offs + 512*OSTR);      // 512*EPG int2

    wtrans<<<dim3(80), dim3(256), 0, stream>>>(W1, W2, Wb1h, Wb1l, Wb2h, Wb2l);

    csr_build<<<dim3(512), dim3(256), 0, stream>>>(
        rowsG, colsG, valsG, rowsB, colsB, valsB,
        rows1, cols1, vals1, rows2, cols2, vals2, offs, pairs);

    gather_all<<<dim3(2816), dim3(256), 0, stream>>>(
        e, f, G_d, B_d, Pd, Qd, w_ae, w_af, offs, pairs, arrs, partials);

    attn_final<<<dim3(1), dim3(128), 0, stream>>>(partials, b_ae, b_af, att);

    final_fused<<<dim3(NTOT/16), dim3(256), 0, stream>>>(
        e, f, arrs, att, Wb1h, Wb1l, Wb2h, Wb2l, b1, b2, (float*)d_out);
}